// Round 4
// baseline (383.337 us; speedup 1.0000x reference)
//
#include <hip/hip_runtime.h>
#include <cstdint>

typedef __attribute__((ext_vector_type(8)))  short short8;
typedef __attribute__((ext_vector_type(16))) float floatx16;

constexpr int NB = 4;        // batch
constexpr int NV = 8192;     // vertices
constexpr int NF = 16384;    // faces
constexpr int NP = 8192;     // query points per batch
constexpr float F_EPS = 1e-3f;
constexpr float F_WEIGHT = 1000.0f;
constexpr float BIAS = 1e-3f;        // keeps dist^2 > 0 despite bf16 rounding

constexpr int PT_TILES = NP / 32;        // 256 point tiles (32-wide) / batch
constexpr int FC_TILES = NF / 32;        // 512 face tiles (32-wide) / batch
constexpr int TPB = 256;                 // 4 waves
constexpr int FS = 16;                   // face slices
constexpr int SL_TILES = FC_TILES / FS;  // 32 face tiles per slice
constexpr int PGS = 64;                  // point groups (128 pts each) / batch
// grid = PGS x FS x NB = 4096 blocks

union FragU { uint4 u; short8 s; };

__device__ inline unsigned f2bf(float f) {           // fp32 -> bf16 (RNE)
    unsigned u = __float_as_uint(f);
    return (u + 0x7FFFu + ((u >> 16) & 1u)) >> 16;
}
__device__ inline float bf2f(unsigned h) { return __uint_as_float(h << 16); }
__device__ inline unsigned pk(unsigned lo, unsigned hi) {
    return (lo & 0xFFFFu) | (hi << 16);
}

// ---------------------------------------------------------------------------
// Fused prep. 32x32x16 MFMA, K=16 fully used. Lane L of a tile holds
// operand[idx = L&31][k = (L>>5)*8 + j], j=0..7 (A: idx=point row m;
// B: idx=face col n). K-slot maps:
//  A (point m): k0..2=-2p_hi k3..5=-2p_lo k6..8=-2p_hi k9..11=-2p_lo
//               k12=1 k13=1 k14=p2b_hi k15=p2b_lo
//  B (face n):  k0..5=c_hi,c_hi  k6..11=c_lo,c_lo  k12=c2_hi k13=c2_lo k14=1 k15=1
//  => D[m][n] = p2b[m] + c2[n] - 2 p.c (all hi/lo cross terms) = dist^2+BIAS > 0
// ---------------------------------------------------------------------------
__global__ void prep_kernel(const float* __restrict__ pred,
                            const float* __restrict__ pos,
                            const int*   __restrict__ faces,
                            uint4* __restrict__ a_frags,
                            uint4* __restrict__ b_frags,
                            float4* __restrict__ centers4,
                            float4* __restrict__ normals4,
                            unsigned* __restrict__ keys,
                            float* __restrict__ acc,
                            unsigned* __restrict__ tk) {
    int i = blockIdx.x * blockDim.x + threadIdx.x;   // [0, NB*NF)
    if (i >= NB * NF) return;
    if (i < 2) acc[i] = 0.0f;
    if (i <= NB * PGS) tk[i] = 0u;                   // group tickets + 1 global

    const unsigned ONE = 0x3F80u;

    // ---- faces ----
    {
        int b = i / NF, f = i & (NF - 1);
        const float* p = pos + (size_t)b * NV * 3;
        int i0 = faces[3 * (size_t)i], i1 = faces[3 * (size_t)i + 1], i2 = faces[3 * (size_t)i + 2];
        float ax = p[3 * i0], ay = p[3 * i0 + 1], az = p[3 * i0 + 2];
        float bx = p[3 * i1], by = p[3 * i1 + 1], bz = p[3 * i1 + 2];
        float cx = p[3 * i2], cy = p[3 * i2 + 1], cz = p[3 * i2 + 2];

        const float third = 1.0f / 3.0f;
        float mx = (ax + bx + cx) * third;
        float my = (ay + by + cy) * third;
        float mz = (az + bz + cz) * third;
        float c2 = mx * mx + my * my + mz * mz;

        float e1x = bx - ax, e1y = by - ay, e1z = bz - az;
        float e2x = cx - ax, e2y = cy - ay, e2z = cz - az;
        float nx = e1y * e2z - e1z * e2y;
        float ny = e1z * e2x - e1x * e2z;
        float nz = e1x * e2y - e1y * e2x;
        float len = sqrtf(nx * nx + ny * ny + nz * nz);
        float inv = 1.0f / fmaxf(len, 1e-12f);

        centers4[i] = make_float4(mx, my, mz, c2);
        normals4[i] = make_float4(nx * inv, ny * inv, nz * inv, 0.0f);

        unsigned bhx = f2bf(mx), bhy = f2bf(my), bhz = f2bf(mz);
        unsigned blx = f2bf(mx - bf2f(bhx)), bly = f2bf(my - bf2f(bhy)), blz = f2bf(mz - bf2f(bhz));
        unsigned c2h = f2bf(c2);
        unsigned c2l = f2bf(c2 - bf2f(c2h));

        int tile = f >> 5, n = f & 31;
        uint4* bb = b_frags + (size_t)(b * FC_TILES + tile) * 64;
        bb[n]      = make_uint4(pk(bhx, bhy), pk(bhz, bhx), pk(bhy, bhz), pk(blx, bly)); // k0..7
        bb[32 + n] = make_uint4(pk(blz, blx), pk(bly, blz), pk(c2h, c2l), pk(ONE, ONE)); // k8..15
    }

    // ---- points ----
    if (i < NB * NP) {
        keys[i] = 0xFFFFFFFFu;
        int pb = i / NP, pn = i & (NP - 1);
        float x = pred[3 * (size_t)i], y = pred[3 * (size_t)i + 1], z = pred[3 * (size_t)i + 2];
        unsigned hx = f2bf(x), hy = f2bf(y), hz = f2bf(z);
        float rx = x - bf2f(hx), ry = y - bf2f(hy), rz = z - bf2f(hz);
        unsigned ahx = f2bf(-2.f * bf2f(hx)), ahy = f2bf(-2.f * bf2f(hy)), ahz = f2bf(-2.f * bf2f(hz));
        unsigned alx = f2bf(-2.f * rx), aly = f2bf(-2.f * ry), alz = f2bf(-2.f * rz);
        float p2 = x * x + y * y + z * z + BIAS;
        unsigned p2h = f2bf(p2);
        unsigned p2l = f2bf(p2 - bf2f(p2h));

        int tile = pn >> 5, m = pn & 31;
        uint4* ab = a_frags + (size_t)(pb * PT_TILES + tile) * 64;
        ab[m]      = make_uint4(pk(ahx, ahy), pk(ahz, alx), pk(aly, alz), pk(ahx, ahy)); // k0..7
        ab[32 + m] = make_uint4(pk(ahz, alx), pk(aly, alz), pk(ONE, ONE), pk(p2h, p2l)); // k8..15
    }
}

// ---------------------------------------------------------------------------
// 1-NN on the matrix pipe, 32x32x16, LDS-free streaming, fused finalize.
// Block = (point group of 128, face slice of 1024, batch); wave owns ONE
// 32-point tile (A in 4 VGPRs, best[16] keys). Face tiles stream from L2 in
// pairs with register prefetch. Epilogue per tile-pair: 32 v_and_or_b32 +
// 16 v_min3_u32 for 2048 pairs. C/D layout (verified m74/m101):
//   col(face) = lane&31, row(point) = (reg&3) + 8*(reg>>2) + 4*(lane>>5).
// key = (bits(dist^2+BIAS) & 0xFFFFC000) | face_idx; cross-slice atomicMin;
// last slice-block per group finalizes; last finalizer writes d_out.
// ---------------------------------------------------------------------------
__global__ __launch_bounds__(TPB) void nn_kernel(
        const float* __restrict__ pred,
        const uint4* __restrict__ a_frags,
        const uint4* __restrict__ b_frags,
        const float4* __restrict__ centers4,
        const float4* __restrict__ normals4,
        unsigned* __restrict__ keys,
        float* __restrict__ acc,
        unsigned* __restrict__ tk,
        float* __restrict__ out) {
    const int pg = blockIdx.x, sl = blockIdx.y, b = blockIdx.z;
    const int tid = threadIdx.x, wave = tid >> 6, lane = tid & 63;

    __shared__ unsigned s_tkt;
    __shared__ float sv[4], sn[4];

    // A fragment: one 32-point tile per wave
    const int pt_tile = pg * 4 + wave;
    FragU a;
    a.u = a_frags[((size_t)(b * PT_TILES + pt_tile)) * 64 + lane];

    unsigned best[16];
#pragma unroll
    for (int e = 0; e < 16; ++e) best[e] = 0xFFFFFFFFu;

    const floatx16 zero = {0.f, 0.f, 0.f, 0.f, 0.f, 0.f, 0.f, 0.f,
                           0.f, 0.f, 0.f, 0.f, 0.f, 0.f, 0.f, 0.f};
    const uint4* bp = b_frags + ((size_t)(b * FC_TILES + sl * SL_TILES)) * 64;
    unsigned vf = (unsigned)(sl * (SL_TILES * 32) + (lane & 31));

    FragU b0, b1, nb0, nb1;
    b0.u = bp[lane];
    b1.u = bp[64 + lane];

    for (int t = 0; t < SL_TILES; t += 2) {
        if (t + 2 < SL_TILES) {
            nb0.u = bp[(t + 2) * 64 + lane];
            nb1.u = bp[(t + 3) * 64 + lane];
        }
        floatx16 d0 = __builtin_amdgcn_mfma_f32_32x32x16_bf16(a.s, b0.s, zero, 0, 0, 0);
        floatx16 d1 = __builtin_amdgcn_mfma_f32_32x32x16_bf16(a.s, b1.s, zero, 0, 0, 0);
#pragma unroll
        for (int r = 0; r < 16; ++r) {
            unsigned k0 = (__float_as_uint(d0[r]) & 0xFFFFC000u) | vf;
            unsigned k1 = (__float_as_uint(d1[r]) & 0xFFFFC000u) | (vf + 32u);
            unsigned m01 = k0 < k1 ? k0 : k1;
            unsigned bb  = best[r];
            best[r] = m01 < bb ? m01 : bb;          // -> v_min3_u32
        }
        vf += 64u;
        b0 = nb0; b1 = nb1;
    }

    // min across the 32 face-columns (lanes within each 32-lane half)
#pragma unroll
    for (int e = 0; e < 16; ++e) {
        unsigned v = best[e];
#pragma unroll
        for (int m = 1; m < 32; m <<= 1) {
            unsigned s = (unsigned)__shfl_xor((int)v, m, 64);
            v = s < v ? s : v;
        }
        best[e] = v;
    }
    unsigned* kb = keys + b * NP;
    if ((lane & 31) == 0) {
        int half = lane >> 5;
#pragma unroll
        for (int r = 0; r < 16; ++r) {
            int row = (r & 3) + 8 * (r >> 2) + 4 * half;
            atomicMin(&kb[pt_tile * 32 + row], best[r]);
        }
    }

    // ---- ticket: last slice-block for this (b,pg) finalizes its 128 points
    __threadfence();
    __syncthreads();                       // all atomicMins of this block done
    if (tid == 0) s_tkt = atomicAdd(&tk[b * PGS + pg], 1u);
    __syncthreads();
    if (s_tkt == FS - 1) {
        float val = 0.0f, cnt = 0.0f;
        if (tid < 128) {
            const int i = b * NP + pg * 128 + tid;
            unsigned key = __hip_atomic_load(&keys[i], __ATOMIC_RELAXED, __HIP_MEMORY_SCOPE_AGENT);
            int idx = (int)(key & (unsigned)(NF - 1));
            float4 c  = centers4[b * NF + idx];
            float4 nr = normals4[b * NF + idx];
            float dx = pred[3 * (size_t)i]     - c.x;
            float dy = pred[3 * (size_t)i + 1] - c.y;
            float dz = pred[3 * (size_t)i + 2] - c.z;
            float dist = dx * nr.x + dy * nr.y + dz * nr.z;
            float tpos = F_EPS - dist;
            if (tpos > 0.0f) { cnt = 1.0f; val = tpos * tpos * tpos; }
        }
        for (int off = 32; off > 0; off >>= 1) {
            val += __shfl_down(val, off, 64);
            cnt += __shfl_down(cnt, off, 64);
        }
        if (lane == 0) { sv[wave] = val; sn[wave] = cnt; }
        __syncthreads();
        if (tid == 0) {
            float v  = sv[0] + sv[1] + sv[2] + sv[3];
            float cc = sn[0] + sn[1] + sn[2] + sn[3];
            atomicAdd(&acc[0], v);
            atomicAdd(&acc[1], cc);
            __threadfence();
            unsigned t2 = atomicAdd(&tk[NB * PGS], 1u);
            if (t2 == (unsigned)(NB * PGS - 1)) {   // last finalizer writes out
                float a0 = __hip_atomic_load(&acc[0], __ATOMIC_RELAXED, __HIP_MEMORY_SCOPE_AGENT);
                float a1 = __hip_atomic_load(&acc[1], __ATOMIC_RELAXED, __HIP_MEMORY_SCOPE_AGENT);
                out[0] = a0 * (F_WEIGHT / (float)NB);
                out[1] = a1 * (1.0f / (float)(NB * NP));
            }
        }
    }
}

extern "C" void kernel_launch(void* const* d_in, const int* in_sizes, int n_in,
                              void* d_out, int out_size, void* d_ws, size_t ws_size,
                              hipStream_t stream) {
    const float* pred  = (const float*)d_in[0];   // [B,N,3] f32
    const float* opos  = (const float*)d_in[1];   // [B,V,3] f32
    const int*   faces = (const int*)  d_in[2];   // [B,F,3] i32

    char* ws = (char*)d_ws;
    const size_t a_bytes = (size_t)NB * PT_TILES * 64 * 16;   // 1 MiB
    const size_t b_bytes = (size_t)NB * FC_TILES * 64 * 16;   // 2 MiB
    const size_t c_bytes = (size_t)NB * NF * 16;              // 1 MiB
    const size_t k_bytes = (size_t)NB * NP * sizeof(unsigned);// 128 KiB

    uint4*    a_frags  = (uint4*)ws;
    uint4*    b_frags  = (uint4*)(ws + a_bytes);
    float4*   centers4 = (float4*)(ws + a_bytes + b_bytes);
    float4*   normals4 = (float4*)(ws + a_bytes + b_bytes + c_bytes);
    unsigned* keys     = (unsigned*)(ws + a_bytes + b_bytes + 2 * c_bytes);
    unsigned* tk       = (unsigned*)(ws + a_bytes + b_bytes + 2 * c_bytes + k_bytes);
    float*    acc      = (float*)(ws + a_bytes + b_bytes + 2 * c_bytes + k_bytes +
                                  ((size_t)(NB * PGS + 1) * sizeof(unsigned) + 15) / 16 * 16);

    prep_kernel<<<(NB * NF + TPB - 1) / TPB, TPB, 0, stream>>>(
        pred, opos, faces, a_frags, b_frags, centers4, normals4, keys, acc, tk);

    nn_kernel<<<dim3(PGS, FS, NB), TPB, 0, stream>>>(
        pred, a_frags, b_frags, centers4, normals4, keys, acc, tk, (float*)d_out);
}

// Round 5
// 234.348 us; speedup vs baseline: 1.6358x; 1.6358x over previous
//
#include <hip/hip_runtime.h>
#include <cstdint>

typedef __attribute__((ext_vector_type(8)))  short short8;
typedef __attribute__((ext_vector_type(16))) float floatx16;

constexpr int NB = 4;        // batch
constexpr int NV = 8192;     // vertices
constexpr int NF = 16384;    // faces
constexpr int NP = 8192;     // query points per batch
constexpr float F_EPS = 1e-3f;
constexpr float F_WEIGHT = 1000.0f;
constexpr float BIAS = 1e-3f;        // keeps dist^2 > 0 despite bf16 rounding

constexpr int PT_TILES = NP / 32;        // 256 point tiles (32-wide) / batch
constexpr int FC_TILES = NF / 32;        // 512 face tiles (32-wide) / batch
constexpr int TPB = 256;                 // 4 waves
constexpr int FS = 8;                    // face slices
constexpr int SL_TILES = FC_TILES / FS;  // 64 face tiles (2048 faces) / slice
constexpr int CH = 16;                   // face tiles per LDS chunk (16 KB)
constexpr int NCHUNK = SL_TILES / CH;    // 4
constexpr int PGS = 64;                  // point groups (128 pts each) / batch
// grid = PGS x FS x NB = 2048 blocks = 8 blocks/CU

union FragU { uint4 u; short8 s; };

__device__ inline unsigned f2bf(float f) {           // fp32 -> bf16 (RNE)
    unsigned u = __float_as_uint(f);
    return (u + 0x7FFFu + ((u >> 16) & 1u)) >> 16;
}
__device__ inline float bf2f(unsigned h) { return __uint_as_float(h << 16); }
__device__ inline unsigned pk(unsigned lo, unsigned hi) {
    return (lo & 0xFFFFu) | (hi << 16);
}

// ---------------------------------------------------------------------------
// Fused prep. 32x32x16 MFMA, K=16 fully used. Lane L of a tile holds
// operand[idx = L&31][k = (L>>5)*8 + j], j=0..7. K-slot maps:
//  A (point m): k0..2=-2p_hi k3..5=-2p_lo k6..8=-2p_hi k9..11=-2p_lo
//               k12=1 k13=1 k14=p2b_hi k15=p2b_lo
//  B (face n):  k0..5=c_hi,c_hi  k6..11=c_lo,c_lo  k12=c2_hi k13=c2_lo k14=1 k15=1
//  => D[m][n] = p2b[m] + c2[n] - 2 p.c = dist^2 + BIAS > 0
// ---------------------------------------------------------------------------
__global__ void prep_kernel(const float* __restrict__ pred,
                            const float* __restrict__ pos,
                            const int*   __restrict__ faces,
                            uint4* __restrict__ a_frags,
                            uint4* __restrict__ b_frags,
                            float4* __restrict__ centers4,
                            float4* __restrict__ normals4,
                            unsigned* __restrict__ keys,
                            float* __restrict__ acc,
                            unsigned* __restrict__ tk) {
    int i = blockIdx.x * blockDim.x + threadIdx.x;   // [0, NB*NF)
    if (i >= NB * NF) return;
    if (i < 2) acc[i] = 0.0f;
    if (i <= NB * PGS) tk[i] = 0u;                   // group tickets + 1 global

    const unsigned ONE = 0x3F80u;

    // ---- faces ----
    {
        int b = i / NF, f = i & (NF - 1);
        const float* p = pos + (size_t)b * NV * 3;
        int i0 = faces[3 * (size_t)i], i1 = faces[3 * (size_t)i + 1], i2 = faces[3 * (size_t)i + 2];
        float ax = p[3 * i0], ay = p[3 * i0 + 1], az = p[3 * i0 + 2];
        float bx = p[3 * i1], by = p[3 * i1 + 1], bz = p[3 * i1 + 2];
        float cx = p[3 * i2], cy = p[3 * i2 + 1], cz = p[3 * i2 + 2];

        const float third = 1.0f / 3.0f;
        float mx = (ax + bx + cx) * third;
        float my = (ay + by + cy) * third;
        float mz = (az + bz + cz) * third;
        float c2 = mx * mx + my * my + mz * mz;

        float e1x = bx - ax, e1y = by - ay, e1z = bz - az;
        float e2x = cx - ax, e2y = cy - ay, e2z = cz - az;
        float nx = e1y * e2z - e1z * e2y;
        float ny = e1z * e2x - e1x * e2z;
        float nz = e1x * e2y - e1y * e2x;
        float len = sqrtf(nx * nx + ny * ny + nz * nz);
        float inv = 1.0f / fmaxf(len, 1e-12f);

        centers4[i] = make_float4(mx, my, mz, c2);
        normals4[i] = make_float4(nx * inv, ny * inv, nz * inv, 0.0f);

        unsigned bhx = f2bf(mx), bhy = f2bf(my), bhz = f2bf(mz);
        unsigned blx = f2bf(mx - bf2f(bhx)), bly = f2bf(my - bf2f(bhy)), blz = f2bf(mz - bf2f(bhz));
        unsigned c2h = f2bf(c2);
        unsigned c2l = f2bf(c2 - bf2f(c2h));

        int tile = f >> 5, n = f & 31;
        uint4* bb = b_frags + (size_t)(b * FC_TILES + tile) * 64;
        bb[n]      = make_uint4(pk(bhx, bhy), pk(bhz, bhx), pk(bhy, bhz), pk(blx, bly)); // k0..7
        bb[32 + n] = make_uint4(pk(blz, blx), pk(bly, blz), pk(c2h, c2l), pk(ONE, ONE)); // k8..15
    }

    // ---- points ----
    if (i < NB * NP) {
        keys[i] = 0xFFFFFFFFu;
        int pb = i / NP, pn = i & (NP - 1);
        float x = pred[3 * (size_t)i], y = pred[3 * (size_t)i + 1], z = pred[3 * (size_t)i + 2];
        unsigned hx = f2bf(x), hy = f2bf(y), hz = f2bf(z);
        float rx = x - bf2f(hx), ry = y - bf2f(hy), rz = z - bf2f(hz);
        unsigned ahx = f2bf(-2.f * bf2f(hx)), ahy = f2bf(-2.f * bf2f(hy)), ahz = f2bf(-2.f * bf2f(hz));
        unsigned alx = f2bf(-2.f * rx), aly = f2bf(-2.f * ry), alz = f2bf(-2.f * rz);
        float p2 = x * x + y * y + z * z + BIAS;
        unsigned p2h = f2bf(p2);
        unsigned p2l = f2bf(p2 - bf2f(p2h));

        int tile = pn >> 5, m = pn & 31;
        uint4* ab = a_frags + (size_t)(pb * PT_TILES + tile) * 64;
        ab[m]      = make_uint4(pk(ahx, ahy), pk(ahz, alx), pk(aly, alz), pk(ahx, ahy)); // k0..7
        ab[32 + m] = make_uint4(pk(ahz, alx), pk(aly, alz), pk(ONE, ONE), pk(p2h, p2l)); // k8..15
    }
}

// ---------------------------------------------------------------------------
// 1-NN on the matrix pipe: 32x32x16 MFMA + LDS-staged B tiles (r2 structure).
// Block = (point group of 128, face slice of 2048, batch); each wave owns ONE
// 32-point A-tile; B-tiles stage through 16KB LDS chunks (block-wide
// coalesced loads, many outstanding), then ds_read_b128 per tile.
// Epilogue per tile-pair: 32 v_and_or_b32 + 16 v_min3_u32 for 2048 pairs.
// C/D layout (verified r4, absmax 0.0):
//   col(face) = lane&31, row(point) = (reg&3) + 8*(reg>>2) + 4*(lane>>5).
// key = (bits(dist^2+BIAS) & 0xFFFFC000) | face_idx; cross-slice atomicMin;
// last slice-block per group finalizes; last finalizer writes d_out.
// ---------------------------------------------------------------------------
__global__ __launch_bounds__(TPB) void nn_kernel(
        const float* __restrict__ pred,
        const uint4* __restrict__ a_frags,
        const uint4* __restrict__ b_frags,
        const float4* __restrict__ centers4,
        const float4* __restrict__ normals4,
        unsigned* __restrict__ keys,
        float* __restrict__ acc,
        unsigned* __restrict__ tk,
        float* __restrict__ out) {
    const int pg = blockIdx.x, sl = blockIdx.y, b = blockIdx.z;
    const int tid = threadIdx.x, wave = tid >> 6, lane = tid & 63;

    __shared__ uint4 sb[CH * 64];        // 16 KB
    __shared__ unsigned s_tkt;
    __shared__ float sv[4], sn[4];

    // A fragment: one 32-point tile per wave
    const int pt_tile = pg * 4 + wave;
    FragU a;
    a.u = a_frags[((size_t)(b * PT_TILES + pt_tile)) * 64 + lane];

    unsigned best[16];
#pragma unroll
    for (int e = 0; e < 16; ++e) best[e] = 0xFFFFFFFFu;

    const floatx16 zero = {0.f, 0.f, 0.f, 0.f, 0.f, 0.f, 0.f, 0.f,
                           0.f, 0.f, 0.f, 0.f, 0.f, 0.f, 0.f, 0.f};
    const uint4* bp = b_frags + ((size_t)(b * FC_TILES + sl * SL_TILES)) * 64;

    for (int ch = 0; ch < NCHUNK; ++ch) {
        const uint4* gsrc = bp + (size_t)ch * CH * 64;
        __syncthreads();                 // previous chunk fully consumed
#pragma unroll
        for (int k = 0; k < (CH * 64) / TPB; ++k)
            sb[k * TPB + tid] = gsrc[k * TPB + tid];
        __syncthreads();

        unsigned vf = (unsigned)((sl * SL_TILES + ch * CH) * 32 + (lane & 31));
#pragma unroll
        for (int t = 0; t < CH; t += 2) {
            FragU b0, b1;
            b0.u = sb[t * 64 + lane];
            b1.u = sb[t * 64 + 64 + lane];
            floatx16 d0 = __builtin_amdgcn_mfma_f32_32x32x16_bf16(a.s, b0.s, zero, 0, 0, 0);
            floatx16 d1 = __builtin_amdgcn_mfma_f32_32x32x16_bf16(a.s, b1.s, zero, 0, 0, 0);
#pragma unroll
            for (int r = 0; r < 16; ++r) {
                unsigned k0 = (__float_as_uint(d0[r]) & 0xFFFFC000u) | vf;
                unsigned k1 = (__float_as_uint(d1[r]) & 0xFFFFC000u) | (vf + 32u);
                unsigned m01 = k0 < k1 ? k0 : k1;
                unsigned bb  = best[r];
                best[r] = m01 < bb ? m01 : bb;          // -> v_min3_u32
            }
            vf += 64u;
        }
    }

    // min across the 32 face-columns (lanes within each 32-lane half)
#pragma unroll
    for (int e = 0; e < 16; ++e) {
        unsigned v = best[e];
#pragma unroll
        for (int m = 1; m < 32; m <<= 1) {
            unsigned s = (unsigned)__shfl_xor((int)v, m, 64);
            v = s < v ? s : v;
        }
        best[e] = v;
    }
    unsigned* kb = keys + b * NP;
    if ((lane & 31) == 0) {
        int half = lane >> 5;
#pragma unroll
        for (int r = 0; r < 16; ++r) {
            int row = (r & 3) + 8 * (r >> 2) + 4 * half;
            atomicMin(&kb[pt_tile * 32 + row], best[r]);
        }
    }

    // ---- ticket: last slice-block for this (b,pg) finalizes its 128 points
    __threadfence();
    __syncthreads();                       // all atomicMins of this block done
    if (tid == 0) s_tkt = atomicAdd(&tk[b * PGS + pg], 1u);
    __syncthreads();
    if (s_tkt == FS - 1) {
        float val = 0.0f, cnt = 0.0f;
        if (tid < 128) {
            const int i = b * NP + pg * 128 + tid;
            unsigned key = __hip_atomic_load(&keys[i], __ATOMIC_RELAXED, __HIP_MEMORY_SCOPE_AGENT);
            int idx = (int)(key & (unsigned)(NF - 1));
            float4 c  = centers4[b * NF + idx];
            float4 nr = normals4[b * NF + idx];
            float dx = pred[3 * (size_t)i]     - c.x;
            float dy = pred[3 * (size_t)i + 1] - c.y;
            float dz = pred[3 * (size_t)i + 2] - c.z;
            float dist = dx * nr.x + dy * nr.y + dz * nr.z;
            float tpos = F_EPS - dist;
            if (tpos > 0.0f) { cnt = 1.0f; val = tpos * tpos * tpos; }
        }
        for (int off = 32; off > 0; off >>= 1) {
            val += __shfl_down(val, off, 64);
            cnt += __shfl_down(cnt, off, 64);
        }
        if (lane == 0) { sv[wave] = val; sn[wave] = cnt; }
        __syncthreads();
        if (tid == 0) {
            float v  = sv[0] + sv[1] + sv[2] + sv[3];
            float cc = sn[0] + sn[1] + sn[2] + sn[3];
            atomicAdd(&acc[0], v);
            atomicAdd(&acc[1], cc);
            __threadfence();
            unsigned t2 = atomicAdd(&tk[NB * PGS], 1u);
            if (t2 == (unsigned)(NB * PGS - 1)) {   // last finalizer writes out
                float a0 = __hip_atomic_load(&acc[0], __ATOMIC_RELAXED, __HIP_MEMORY_SCOPE_AGENT);
                float a1 = __hip_atomic_load(&acc[1], __ATOMIC_RELAXED, __HIP_MEMORY_SCOPE_AGENT);
                out[0] = a0 * (F_WEIGHT / (float)NB);
                out[1] = a1 * (1.0f / (float)(NB * NP));
            }
        }
    }
}

extern "C" void kernel_launch(void* const* d_in, const int* in_sizes, int n_in,
                              void* d_out, int out_size, void* d_ws, size_t ws_size,
                              hipStream_t stream) {
    const float* pred  = (const float*)d_in[0];   // [B,N,3] f32
    const float* opos  = (const float*)d_in[1];   // [B,V,3] f32
    const int*   faces = (const int*)  d_in[2];   // [B,F,3] i32

    char* ws = (char*)d_ws;
    const size_t a_bytes = (size_t)NB * PT_TILES * 64 * 16;   // 1 MiB
    const size_t b_bytes = (size_t)NB * FC_TILES * 64 * 16;   // 2 MiB
    const size_t c_bytes = (size_t)NB * NF * 16;              // 1 MiB
    const size_t k_bytes = (size_t)NB * NP * sizeof(unsigned);// 128 KiB

    uint4*    a_frags  = (uint4*)ws;
    uint4*    b_frags  = (uint4*)(ws + a_bytes);
    float4*   centers4 = (float4*)(ws + a_bytes + b_bytes);
    float4*   normals4 = (float4*)(ws + a_bytes + b_bytes + c_bytes);
    unsigned* keys     = (unsigned*)(ws + a_bytes + b_bytes + 2 * c_bytes);
    unsigned* tk       = (unsigned*)(ws + a_bytes + b_bytes + 2 * c_bytes + k_bytes);
    float*    acc      = (float*)(ws + a_bytes + b_bytes + 2 * c_bytes + k_bytes +
                                  ((size_t)(NB * PGS + 1) * sizeof(unsigned) + 15) / 16 * 16);

    prep_kernel<<<(NB * NF + TPB - 1) / TPB, TPB, 0, stream>>>(
        pred, opos, faces, a_frags, b_frags, centers4, normals4, keys, acc, tk);

    nn_kernel<<<dim3(PGS, FS, NB), TPB, 0, stream>>>(
        pred, a_frags, b_frags, centers4, normals4, keys, acc, tk, (float*)d_out);
}

// Round 6
// 113.436 us; speedup vs baseline: 3.3793x; 2.0659x over previous
//
#include <hip/hip_runtime.h>
#include <cstdint>

typedef __attribute__((ext_vector_type(8)))  short short8;
typedef __attribute__((ext_vector_type(16))) float floatx16;

constexpr int NB = 4;        // batch
constexpr int NV = 8192;     // vertices
constexpr int NF = 16384;    // faces
constexpr int NP = 8192;     // query points per batch
constexpr float F_EPS = 1e-3f;
constexpr float F_WEIGHT = 1000.0f;
constexpr float BIAS = 1e-3f;        // keeps dist^2 > 0 despite bf16 rounding

constexpr int PT_TILES = NP / 32;        // 256 point tiles (32-wide) / batch
constexpr int FC_TILES = NF / 32;        // 512 face tiles (32-wide) / batch
constexpr int TPB = 256;                 // 4 waves
constexpr int FS = 8;                    // face slices
constexpr int SL_TILES = FC_TILES / FS;  // 64 face tiles (2048 faces) / slice
constexpr int CH = 16;                   // face tiles per LDS chunk (16 KB)
constexpr int NCHUNK = SL_TILES / CH;    // 4
constexpr int PGB = 32;                  // point groups (256 pts) / batch
// grid = PGB x FS x NB = 1024 blocks = 4 blocks/CU

union FragU { uint4 u; short8 s; };

__device__ inline unsigned f2bf(float f) {           // fp32 -> bf16 (RNE)
    unsigned u = __float_as_uint(f);
    return (u + 0x7FFFu + ((u >> 16) & 1u)) >> 16;
}
__device__ inline float bf2f(unsigned h) { return __uint_as_float(h << 16); }
__device__ inline unsigned pk(unsigned lo, unsigned hi) {
    return (lo & 0xFFFFu) | (hi << 16);
}

// ---------------------------------------------------------------------------
// Fused prep. 32x32x16 MFMA, K=16 fully used. Lane L of an operand tile holds
// elem[idx = L&31][k = (L>>5)*8 + j], j=0..7. K-slot maps:
//  A (point m): k0..2=-2p_hi k3..5=-2p_lo k6..8=-2p_hi k9..11=-2p_lo
//               k12=1 k13=1 k14=p2b_hi k15=p2b_lo
//  B (face n):  k0..5=c_hi,c_hi  k6..11=c_lo,c_lo  k12=c2_hi k13=c2_lo k14=1 k15=1
//  => D[m][n] = p2b[m] + c2[n] - 2 p.c = dist^2 + BIAS > 0
// Also inits keys (0xFF) and acc (0) -- no separate memsets.
// ---------------------------------------------------------------------------
__global__ void prep_kernel(const float* __restrict__ pred,
                            const float* __restrict__ pos,
                            const int*   __restrict__ faces,
                            uint4* __restrict__ a_frags,
                            uint4* __restrict__ b_frags,
                            float4* __restrict__ centers4,
                            float4* __restrict__ normals4,
                            unsigned* __restrict__ keys,
                            float* __restrict__ acc) {
    int i = blockIdx.x * blockDim.x + threadIdx.x;   // [0, NB*NF)
    if (i >= NB * NF) return;
    if (i < 2) acc[i] = 0.0f;

    const unsigned ONE = 0x3F80u;

    // ---- faces ----
    {
        int b = i / NF, f = i & (NF - 1);
        const float* p = pos + (size_t)b * NV * 3;
        int i0 = faces[3 * (size_t)i], i1 = faces[3 * (size_t)i + 1], i2 = faces[3 * (size_t)i + 2];
        float ax = p[3 * i0], ay = p[3 * i0 + 1], az = p[3 * i0 + 2];
        float bx = p[3 * i1], by = p[3 * i1 + 1], bz = p[3 * i1 + 2];
        float cx = p[3 * i2], cy = p[3 * i2 + 1], cz = p[3 * i2 + 2];

        const float third = 1.0f / 3.0f;
        float mx = (ax + bx + cx) * third;
        float my = (ay + by + cy) * third;
        float mz = (az + bz + cz) * third;
        float c2 = mx * mx + my * my + mz * mz;

        float e1x = bx - ax, e1y = by - ay, e1z = bz - az;
        float e2x = cx - ax, e2y = cy - ay, e2z = cz - az;
        float nx = e1y * e2z - e1z * e2y;
        float ny = e1z * e2x - e1x * e2z;
        float nz = e1x * e2y - e1y * e2x;
        float len = sqrtf(nx * nx + ny * ny + nz * nz);
        float inv = 1.0f / fmaxf(len, 1e-12f);

        centers4[i] = make_float4(mx, my, mz, c2);
        normals4[i] = make_float4(nx * inv, ny * inv, nz * inv, 0.0f);

        unsigned bhx = f2bf(mx), bhy = f2bf(my), bhz = f2bf(mz);
        unsigned blx = f2bf(mx - bf2f(bhx)), bly = f2bf(my - bf2f(bhy)), blz = f2bf(mz - bf2f(bhz));
        unsigned c2h = f2bf(c2);
        unsigned c2l = f2bf(c2 - bf2f(c2h));

        int tile = f >> 5, n = f & 31;
        uint4* bb = b_frags + (size_t)(b * FC_TILES + tile) * 64;
        bb[n]      = make_uint4(pk(bhx, bhy), pk(bhz, bhx), pk(bhy, bhz), pk(blx, bly)); // k0..7
        bb[32 + n] = make_uint4(pk(blz, blx), pk(bly, blz), pk(c2h, c2l), pk(ONE, ONE)); // k8..15
    }

    // ---- points ----
    if (i < NB * NP) {
        keys[i] = 0xFFFFFFFFu;
        int pb = i / NP, pn = i & (NP - 1);
        float x = pred[3 * (size_t)i], y = pred[3 * (size_t)i + 1], z = pred[3 * (size_t)i + 2];
        unsigned hx = f2bf(x), hy = f2bf(y), hz = f2bf(z);
        float rx = x - bf2f(hx), ry = y - bf2f(hy), rz = z - bf2f(hz);
        unsigned ahx = f2bf(-2.f * bf2f(hx)), ahy = f2bf(-2.f * bf2f(hy)), ahz = f2bf(-2.f * bf2f(hz));
        unsigned alx = f2bf(-2.f * rx), aly = f2bf(-2.f * ry), alz = f2bf(-2.f * rz);
        float p2 = x * x + y * y + z * z + BIAS;
        unsigned p2h = f2bf(p2);
        unsigned p2l = f2bf(p2 - bf2f(p2h));

        int tile = pn >> 5, m = pn & 31;
        uint4* ab = a_frags + (size_t)(pb * PT_TILES + tile) * 64;
        ab[m]      = make_uint4(pk(ahx, ahy), pk(ahz, alx), pk(aly, alz), pk(ahx, ahy)); // k0..7
        ab[32 + m] = make_uint4(pk(ahz, alx), pk(aly, alz), pk(ONE, ONE), pk(p2h, p2l)); // k8..15
    }
}

// ---------------------------------------------------------------------------
// 1-NN on the matrix pipe: 32x32x16 MFMA + LDS-staged B tiles, r2's proven
// dispatch shape (NO fence/ticket tail). Block = (256 points, 2048-face
// slice, batch); each wave owns TWO 32-point A-tiles. Per face-tile pair:
// 4 MFMAs, epilogue 64 v_and_or_b32 + 32 v_min3_u32 for 4096 pairs.
// C/D layout (verified r4/r5, absmax 0.0):
//   col(face) = lane&31, row(point) = (reg&3) + 8*(reg>>2) + 4*(lane>>5).
// key = (bits(dist^2+BIAS) & 0xFFFFC000) | face_idx; cross-slice atomicMin.
// ---------------------------------------------------------------------------
__global__ __launch_bounds__(TPB) void nn_kernel(
        const uint4* __restrict__ a_frags,
        const uint4* __restrict__ b_frags,
        unsigned* __restrict__ keys) {
    const int pg = blockIdx.x, sl = blockIdx.y, b = blockIdx.z;
    const int tid = threadIdx.x, wave = tid >> 6, lane = tid & 63;

    __shared__ uint4 sb[CH * 64];        // 16 KB

    // two 32-point A-tiles per wave
    const int t0 = pg * 8 + wave * 2;
    FragU a0, a1;
    a0.u = a_frags[((size_t)(b * PT_TILES + t0)) * 64 + lane];
    a1.u = a_frags[((size_t)(b * PT_TILES + t0 + 1)) * 64 + lane];

    unsigned best0[16], best1[16];
#pragma unroll
    for (int e = 0; e < 16; ++e) { best0[e] = 0xFFFFFFFFu; best1[e] = 0xFFFFFFFFu; }

    const floatx16 zero = {0.f, 0.f, 0.f, 0.f, 0.f, 0.f, 0.f, 0.f,
                           0.f, 0.f, 0.f, 0.f, 0.f, 0.f, 0.f, 0.f};
    const uint4* bp = b_frags + ((size_t)(b * FC_TILES + sl * SL_TILES)) * 64;

    for (int ch = 0; ch < NCHUNK; ++ch) {
        const uint4* gsrc = bp + (size_t)ch * CH * 64;
        __syncthreads();                 // previous chunk fully consumed
#pragma unroll
        for (int k = 0; k < (CH * 64) / TPB; ++k)
            sb[k * TPB + tid] = gsrc[k * TPB + tid];
        __syncthreads();

        unsigned vf = (unsigned)((sl * SL_TILES + ch * CH) * 32 + (lane & 31));
#pragma unroll
        for (int t = 0; t < CH; t += 2) {
            FragU fb0, fb1;
            fb0.u = sb[t * 64 + lane];
            fb1.u = sb[t * 64 + 64 + lane];
            floatx16 d00 = __builtin_amdgcn_mfma_f32_32x32x16_bf16(a0.s, fb0.s, zero, 0, 0, 0);
            floatx16 d01 = __builtin_amdgcn_mfma_f32_32x32x16_bf16(a0.s, fb1.s, zero, 0, 0, 0);
#pragma unroll
            for (int r = 0; r < 16; ++r) {
                unsigned k0 = (__float_as_uint(d00[r]) & 0xFFFFC000u) | vf;
                unsigned k1 = (__float_as_uint(d01[r]) & 0xFFFFC000u) | (vf + 32u);
                unsigned m01 = k0 < k1 ? k0 : k1;
                unsigned bb  = best0[r];
                best0[r] = m01 < bb ? m01 : bb;          // -> v_min3_u32
            }
            floatx16 d10 = __builtin_amdgcn_mfma_f32_32x32x16_bf16(a1.s, fb0.s, zero, 0, 0, 0);
            floatx16 d11 = __builtin_amdgcn_mfma_f32_32x32x16_bf16(a1.s, fb1.s, zero, 0, 0, 0);
#pragma unroll
            for (int r = 0; r < 16; ++r) {
                unsigned k0 = (__float_as_uint(d10[r]) & 0xFFFFC000u) | vf;
                unsigned k1 = (__float_as_uint(d11[r]) & 0xFFFFC000u) | (vf + 32u);
                unsigned m01 = k0 < k1 ? k0 : k1;
                unsigned bb  = best1[r];
                best1[r] = m01 < bb ? m01 : bb;
            }
            vf += 64u;
        }
    }

    // min across the 32 face-columns (stays within each 32-lane half)
#pragma unroll
    for (int e = 0; e < 16; ++e) {
        unsigned v0 = best0[e], v1 = best1[e];
#pragma unroll
        for (int m = 1; m < 32; m <<= 1) {
            unsigned s0 = (unsigned)__shfl_xor((int)v0, m, 64);
            unsigned s1 = (unsigned)__shfl_xor((int)v1, m, 64);
            v0 = s0 < v0 ? s0 : v0;
            v1 = s1 < v1 ? s1 : v1;
        }
        best0[e] = v0; best1[e] = v1;
    }
    unsigned* kb = keys + b * NP;
    if ((lane & 31) == 0) {
        int half = lane >> 5;
#pragma unroll
        for (int r = 0; r < 16; ++r) {
            int row = (r & 3) + 8 * (r >> 2) + 4 * half;
            atomicMin(&kb[t0 * 32 + row], best0[r]);
            atomicMin(&kb[(t0 + 1) * 32 + row], best1[r]);
        }
    }
}

// ---------------------------------------------------------------------------
// Per-point signed plane distance -> interp^3 sum + hit count (r2-proven).
// ---------------------------------------------------------------------------
__global__ __launch_bounds__(TPB) void finalize_kernel(
        const float* __restrict__ pred,
        const float4* __restrict__ centers4,
        const float4* __restrict__ normals4,
        const unsigned int* __restrict__ keys,
        float* __restrict__ acc) {
    int i = blockIdx.x * blockDim.x + threadIdx.x;   // 0 .. B*N-1
    float val = 0.0f, cnt = 0.0f;
    if (i < NB * NP) {
        int b = i / NP;
        unsigned key = keys[i];
        int idx = (int)(key & (unsigned)(NF - 1));
        float4 c  = centers4[b * NF + idx];
        float4 nr = normals4[b * NF + idx];
        const float* pp = pred + (size_t)i * 3;
        float dx = pp[0] - c.x, dy = pp[1] - c.y, dz = pp[2] - c.z;
        float dist = dx * nr.x + dy * nr.y + dz * nr.z;
        float t = F_EPS - dist;
        if (t > 0.0f) { cnt = 1.0f; val = t * t * t; }
    }
    for (int off = 32; off > 0; off >>= 1) {
        val += __shfl_down(val, off, 64);
        cnt += __shfl_down(cnt, off, 64);
    }
    __shared__ float sv[TPB / 64], sn[TPB / 64];
    int lane = threadIdx.x & 63, wave = threadIdx.x >> 6;
    if (lane == 0) { sv[wave] = val; sn[wave] = cnt; }
    __syncthreads();
    if (threadIdx.x == 0) {
        float v = 0.0f, cc = 0.0f;
#pragma unroll
        for (int w = 0; w < TPB / 64; ++w) { v += sv[w]; cc += sn[w]; }
        atomicAdd(&acc[0], v);
        atomicAdd(&acc[1], cc);
    }
}

__global__ void out_kernel(const float* __restrict__ acc,
                           float* __restrict__ out) {
    if (threadIdx.x == 0) {
        out[0] = acc[0] * (F_WEIGHT / (float)NB);
        out[1] = acc[1] * (1.0f / (float)(NB * NP));
    }
}

extern "C" void kernel_launch(void* const* d_in, const int* in_sizes, int n_in,
                              void* d_out, int out_size, void* d_ws, size_t ws_size,
                              hipStream_t stream) {
    const float* pred  = (const float*)d_in[0];   // [B,N,3] f32
    const float* opos  = (const float*)d_in[1];   // [B,V,3] f32
    const int*   faces = (const int*)  d_in[2];   // [B,F,3] i32

    char* ws = (char*)d_ws;
    const size_t a_bytes = (size_t)NB * PT_TILES * 64 * 16;   // 1 MiB
    const size_t b_bytes = (size_t)NB * FC_TILES * 64 * 16;   // 2 MiB
    const size_t c_bytes = (size_t)NB * NF * 16;              // 1 MiB
    const size_t k_bytes = (size_t)NB * NP * sizeof(unsigned);// 128 KiB

    uint4*    a_frags  = (uint4*)ws;
    uint4*    b_frags  = (uint4*)(ws + a_bytes);
    float4*   centers4 = (float4*)(ws + a_bytes + b_bytes);
    float4*   normals4 = (float4*)(ws + a_bytes + b_bytes + c_bytes);
    unsigned* keys     = (unsigned*)(ws + a_bytes + b_bytes + 2 * c_bytes);
    float*    acc      = (float*)(ws + a_bytes + b_bytes + 2 * c_bytes + k_bytes);

    prep_kernel<<<(NB * NF + TPB - 1) / TPB, TPB, 0, stream>>>(
        pred, opos, faces, a_frags, b_frags, centers4, normals4, keys, acc);

    nn_kernel<<<dim3(PGB, FS, NB), TPB, 0, stream>>>(a_frags, b_frags, keys);

    finalize_kernel<<<(NB * NP + TPB - 1) / TPB, TPB, 0, stream>>>(
        pred, centers4, normals4, keys, acc);

    out_kernel<<<1, 64, 0, stream>>>(acc, (float*)d_out);
}

// Round 7
// 113.395 us; speedup vs baseline: 3.3805x; 1.0004x over previous
//
#include <hip/hip_runtime.h>
#include <cstdint>

typedef __attribute__((ext_vector_type(8)))  short short8;
typedef __attribute__((ext_vector_type(16))) float floatx16;

constexpr int NB = 4;        // batch
constexpr int NV = 8192;     // vertices
constexpr int NF = 16384;    // faces
constexpr int NP = 8192;     // query points per batch
constexpr float F_EPS = 1e-3f;
constexpr float F_WEIGHT = 1000.0f;
constexpr float BIAS = 1e-3f;        // keeps dist^2 > 0 despite bf16 rounding

constexpr int PT_TILES = NP / 32;        // 256 point tiles (32-wide) / batch
constexpr int FC_TILES = NF / 32;        // 512 face tiles (32-wide) / batch
constexpr int TPB = 256;                 // 4 waves
constexpr int FS = 16;                   // face slices
constexpr int SL_TILES = FC_TILES / FS;  // 32 face tiles (1024 faces) / slice
constexpr int CH = 16;                   // face tiles per LDS chunk (16 KB)
constexpr int NCHUNK = SL_TILES / CH;    // 2
constexpr int PGB = 32;                  // point groups (256 pts) / batch
// grid = PGB x FS x NB = 2048 blocks = 8 blocks/CU

union FragU { uint4 u; short8 s; };

__device__ inline unsigned f2bf(float f) {           // fp32 -> bf16 (RNE)
    unsigned u = __float_as_uint(f);
    return (u + 0x7FFFu + ((u >> 16) & 1u)) >> 16;
}
__device__ inline float bf2f(unsigned h) { return __uint_as_float(h << 16); }
__device__ inline unsigned pk(unsigned lo, unsigned hi) {
    return (lo & 0xFFFFu) | (hi << 16);
}

// ---------------------------------------------------------------------------
// Fused prep. 32x32x16 MFMA, K=16 fully used. Lane L of an operand tile holds
// elem[idx = L&31][k = (L>>5)*8 + j], j=0..7. K-slot maps:
//  A (point m): k0..2=-2p_hi k3..5=-2p_lo k6..8=-2p_hi k9..11=-2p_lo
//               k12=1 k13=1 k14=p2b_hi k15=p2b_lo
//  B (face n):  k0..5=c_hi,c_hi  k6..11=c_lo,c_lo  k12=c2_hi k13=c2_lo k14=1 k15=1
//  => D[m][n] = p2b[m] + c2[n] - 2 p.c = dist^2 + BIAS > 0
// Also inits keys (0xFF) and acc (0) -- no separate memsets.
// ---------------------------------------------------------------------------
__global__ void prep_kernel(const float* __restrict__ pred,
                            const float* __restrict__ pos,
                            const int*   __restrict__ faces,
                            uint4* __restrict__ a_frags,
                            uint4* __restrict__ b_frags,
                            float4* __restrict__ centers4,
                            float4* __restrict__ normals4,
                            unsigned* __restrict__ keys,
                            float* __restrict__ acc) {
    int i = blockIdx.x * blockDim.x + threadIdx.x;   // [0, NB*NF)
    if (i >= NB * NF) return;
    if (i < 2) acc[i] = 0.0f;

    const unsigned ONE = 0x3F80u;

    // ---- faces ----
    {
        int b = i / NF, f = i & (NF - 1);
        const float* p = pos + (size_t)b * NV * 3;
        int i0 = faces[3 * (size_t)i], i1 = faces[3 * (size_t)i + 1], i2 = faces[3 * (size_t)i + 2];
        float ax = p[3 * i0], ay = p[3 * i0 + 1], az = p[3 * i0 + 2];
        float bx = p[3 * i1], by = p[3 * i1 + 1], bz = p[3 * i1 + 2];
        float cx = p[3 * i2], cy = p[3 * i2 + 1], cz = p[3 * i2 + 2];

        const float third = 1.0f / 3.0f;
        float mx = (ax + bx + cx) * third;
        float my = (ay + by + cy) * third;
        float mz = (az + bz + cz) * third;
        float c2 = mx * mx + my * my + mz * mz;

        float e1x = bx - ax, e1y = by - ay, e1z = bz - az;
        float e2x = cx - ax, e2y = cy - ay, e2z = cz - az;
        float nx = e1y * e2z - e1z * e2y;
        float ny = e1z * e2x - e1x * e2z;
        float nz = e1x * e2y - e1y * e2x;
        float len = sqrtf(nx * nx + ny * ny + nz * nz);
        float inv = 1.0f / fmaxf(len, 1e-12f);

        centers4[i] = make_float4(mx, my, mz, c2);
        normals4[i] = make_float4(nx * inv, ny * inv, nz * inv, 0.0f);

        unsigned bhx = f2bf(mx), bhy = f2bf(my), bhz = f2bf(mz);
        unsigned blx = f2bf(mx - bf2f(bhx)), bly = f2bf(my - bf2f(bhy)), blz = f2bf(mz - bf2f(bhz));
        unsigned c2h = f2bf(c2);
        unsigned c2l = f2bf(c2 - bf2f(c2h));

        int tile = f >> 5, n = f & 31;
        uint4* bb = b_frags + (size_t)(b * FC_TILES + tile) * 64;
        bb[n]      = make_uint4(pk(bhx, bhy), pk(bhz, bhx), pk(bhy, bhz), pk(blx, bly)); // k0..7
        bb[32 + n] = make_uint4(pk(blz, blx), pk(bly, blz), pk(c2h, c2l), pk(ONE, ONE)); // k8..15
    }

    // ---- points ----
    if (i < NB * NP) {
        keys[i] = 0xFFFFFFFFu;
        int pb = i / NP, pn = i & (NP - 1);
        float x = pred[3 * (size_t)i], y = pred[3 * (size_t)i + 1], z = pred[3 * (size_t)i + 2];
        unsigned hx = f2bf(x), hy = f2bf(y), hz = f2bf(z);
        float rx = x - bf2f(hx), ry = y - bf2f(hy), rz = z - bf2f(hz);
        unsigned ahx = f2bf(-2.f * bf2f(hx)), ahy = f2bf(-2.f * bf2f(hy)), ahz = f2bf(-2.f * bf2f(hz));
        unsigned alx = f2bf(-2.f * rx), aly = f2bf(-2.f * ry), alz = f2bf(-2.f * rz);
        float p2 = x * x + y * y + z * z + BIAS;
        unsigned p2h = f2bf(p2);
        unsigned p2l = f2bf(p2 - bf2f(p2h));

        int tile = pn >> 5, m = pn & 31;
        uint4* ab = a_frags + (size_t)(pb * PT_TILES + tile) * 64;
        ab[m]      = make_uint4(pk(ahx, ahy), pk(ahz, alx), pk(aly, alz), pk(ahx, ahy)); // k0..7
        ab[32 + m] = make_uint4(pk(ahz, alx), pk(aly, alz), pk(ONE, ONE), pk(p2h, p2l)); // k8..15
    }
}

// ---------------------------------------------------------------------------
// 1-NN on the matrix pipe: 32x32x16 MFMA + LDS-staged B tiles, r6 structure
// with (1) explicit min() -> v_min_u32/v_min3_u32 codegen (the r6 ternary
// lowered to cmp+cndmask, 3.4x VALU inflation), (2) FS=16 for 8 blocks/CU.
// Block = (256 points, 1024-face slice, batch); each wave owns TWO 32-point
// A-tiles. C/D layout (verified r4-r6, absmax 0.0):
//   col(face) = lane&31, row(point) = (reg&3) + 8*(reg>>2) + 4*(lane>>5).
// key = (bits(dist^2+BIAS) & 0xFFFFC000) | face_idx; cross-slice atomicMin.
// ---------------------------------------------------------------------------
__global__ __launch_bounds__(TPB) void nn_kernel(
        const uint4* __restrict__ a_frags,
        const uint4* __restrict__ b_frags,
        unsigned* __restrict__ keys) {
    const int pg = blockIdx.x, sl = blockIdx.y, b = blockIdx.z;
    const int tid = threadIdx.x, wave = tid >> 6, lane = tid & 63;

    __shared__ uint4 sb[CH * 64];        // 16 KB

    // two 32-point A-tiles per wave
    const int t0 = pg * 8 + wave * 2;
    FragU a0, a1;
    a0.u = a_frags[((size_t)(b * PT_TILES + t0)) * 64 + lane];
    a1.u = a_frags[((size_t)(b * PT_TILES + t0 + 1)) * 64 + lane];

    unsigned best0[16], best1[16];
#pragma unroll
    for (int e = 0; e < 16; ++e) { best0[e] = 0xFFFFFFFFu; best1[e] = 0xFFFFFFFFu; }

    const floatx16 zero = {0.f, 0.f, 0.f, 0.f, 0.f, 0.f, 0.f, 0.f,
                           0.f, 0.f, 0.f, 0.f, 0.f, 0.f, 0.f, 0.f};
    const uint4* bp = b_frags + ((size_t)(b * FC_TILES + sl * SL_TILES)) * 64;

    for (int ch = 0; ch < NCHUNK; ++ch) {
        const uint4* gsrc = bp + (size_t)ch * CH * 64;
        __syncthreads();                 // previous chunk fully consumed
#pragma unroll
        for (int k = 0; k < (CH * 64) / TPB; ++k)
            sb[k * TPB + tid] = gsrc[k * TPB + tid];
        __syncthreads();

        unsigned vf = (unsigned)((sl * SL_TILES + ch * CH) * 32 + (lane & 31));
#pragma unroll
        for (int t = 0; t < CH; t += 2) {
            FragU fb0, fb1;
            fb0.u = sb[t * 64 + lane];
            fb1.u = sb[t * 64 + 64 + lane];
            floatx16 d00 = __builtin_amdgcn_mfma_f32_32x32x16_bf16(a0.s, fb0.s, zero, 0, 0, 0);
            floatx16 d01 = __builtin_amdgcn_mfma_f32_32x32x16_bf16(a0.s, fb1.s, zero, 0, 0, 0);
#pragma unroll
            for (int r = 0; r < 16; ++r) {
                unsigned k0 = (__float_as_uint(d00[r]) & 0xFFFFC000u) | vf;
                unsigned k1 = (__float_as_uint(d01[r]) & 0xFFFFC000u) | (vf + 32u);
                best0[r] = min(best0[r], min(k0, k1));   // -> v_min3_u32
            }
            floatx16 d10 = __builtin_amdgcn_mfma_f32_32x32x16_bf16(a1.s, fb0.s, zero, 0, 0, 0);
            floatx16 d11 = __builtin_amdgcn_mfma_f32_32x32x16_bf16(a1.s, fb1.s, zero, 0, 0, 0);
#pragma unroll
            for (int r = 0; r < 16; ++r) {
                unsigned k0 = (__float_as_uint(d10[r]) & 0xFFFFC000u) | vf;
                unsigned k1 = (__float_as_uint(d11[r]) & 0xFFFFC000u) | (vf + 32u);
                best1[r] = min(best1[r], min(k0, k1));
            }
            vf += 64u;
        }
    }

    // min across the 32 face-columns (stays within each 32-lane half)
#pragma unroll
    for (int e = 0; e < 16; ++e) {
        unsigned v0 = best0[e], v1 = best1[e];
#pragma unroll
        for (int m = 1; m < 32; m <<= 1) {
            v0 = min(v0, (unsigned)__shfl_xor((int)v0, m, 64));
            v1 = min(v1, (unsigned)__shfl_xor((int)v1, m, 64));
        }
        best0[e] = v0; best1[e] = v1;
    }
    unsigned* kb = keys + b * NP;
    if ((lane & 31) == 0) {
        int half = lane >> 5;
#pragma unroll
        for (int r = 0; r < 16; ++r) {
            int row = (r & 3) + 8 * (r >> 2) + 4 * half;
            atomicMin(&kb[t0 * 32 + row], best0[r]);
            atomicMin(&kb[(t0 + 1) * 32 + row], best1[r]);
        }
    }
}

// ---------------------------------------------------------------------------
// Per-point signed plane distance -> interp^3 sum + hit count (r2-proven).
// ---------------------------------------------------------------------------
__global__ __launch_bounds__(TPB) void finalize_kernel(
        const float* __restrict__ pred,
        const float4* __restrict__ centers4,
        const float4* __restrict__ normals4,
        const unsigned int* __restrict__ keys,
        float* __restrict__ acc) {
    int i = blockIdx.x * blockDim.x + threadIdx.x;   // 0 .. B*N-1
    float val = 0.0f, cnt = 0.0f;
    if (i < NB * NP) {
        int b = i / NP;
        unsigned key = keys[i];
        int idx = (int)(key & (unsigned)(NF - 1));
        float4 c  = centers4[b * NF + idx];
        float4 nr = normals4[b * NF + idx];
        const float* pp = pred + (size_t)i * 3;
        float dx = pp[0] - c.x, dy = pp[1] - c.y, dz = pp[2] - c.z;
        float dist = dx * nr.x + dy * nr.y + dz * nr.z;
        float t = F_EPS - dist;
        if (t > 0.0f) { cnt = 1.0f; val = t * t * t; }
    }
    for (int off = 32; off > 0; off >>= 1) {
        val += __shfl_down(val, off, 64);
        cnt += __shfl_down(cnt, off, 64);
    }
    __shared__ float sv[TPB / 64], sn[TPB / 64];
    int lane = threadIdx.x & 63, wave = threadIdx.x >> 6;
    if (lane == 0) { sv[wave] = val; sn[wave] = cnt; }
    __syncthreads();
    if (threadIdx.x == 0) {
        float v = 0.0f, cc = 0.0f;
#pragma unroll
        for (int w = 0; w < TPB / 64; ++w) { v += sv[w]; cc += sn[w]; }
        atomicAdd(&acc[0], v);
        atomicAdd(&acc[1], cc);
    }
}

__global__ void out_kernel(const float* __restrict__ acc,
                           float* __restrict__ out) {
    if (threadIdx.x == 0) {
        out[0] = acc[0] * (F_WEIGHT / (float)NB);
        out[1] = acc[1] * (1.0f / (float)(NB * NP));
    }
}

extern "C" void kernel_launch(void* const* d_in, const int* in_sizes, int n_in,
                              void* d_out, int out_size, void* d_ws, size_t ws_size,
                              hipStream_t stream) {
    const float* pred  = (const float*)d_in[0];   // [B,N,3] f32
    const float* opos  = (const float*)d_in[1];   // [B,V,3] f32
    const int*   faces = (const int*)  d_in[2];   // [B,F,3] i32

    char* ws = (char*)d_ws;
    const size_t a_bytes = (size_t)NB * PT_TILES * 64 * 16;   // 1 MiB
    const size_t b_bytes = (size_t)NB * FC_TILES * 64 * 16;   // 2 MiB
    const size_t c_bytes = (size_t)NB * NF * 16;              // 1 MiB
    const size_t k_bytes = (size_t)NB * NP * sizeof(unsigned);// 128 KiB

    uint4*    a_frags  = (uint4*)ws;
    uint4*    b_frags  = (uint4*)(ws + a_bytes);
    float4*   centers4 = (float4*)(ws + a_bytes + b_bytes);
    float4*   normals4 = (float4*)(ws + a_bytes + b_bytes + c_bytes);
    unsigned* keys     = (unsigned*)(ws + a_bytes + b_bytes + 2 * c_bytes);
    float*    acc      = (float*)(ws + a_bytes + b_bytes + 2 * c_bytes + k_bytes);

    prep_kernel<<<(NB * NF + TPB - 1) / TPB, TPB, 0, stream>>>(
        pred, opos, faces, a_frags, b_frags, centers4, normals4, keys, acc);

    nn_kernel<<<dim3(PGB, FS, NB), TPB, 0, stream>>>(a_frags, b_frags, keys);

    finalize_kernel<<<(NB * NP + TPB - 1) / TPB, TPB, 0, stream>>>(
        pred, centers4, normals4, keys, acc);

    out_kernel<<<1, 64, 0, stream>>>(acc, (float*)d_out);
}

// Round 8
// 112.592 us; speedup vs baseline: 3.4047x; 1.0071x over previous
//
#include <hip/hip_runtime.h>
#include <cstdint>

typedef __attribute__((ext_vector_type(8)))  short short8;
typedef __attribute__((ext_vector_type(16))) float floatx16;

constexpr int NB = 4;        // batch
constexpr int NV = 8192;     // vertices
constexpr int NF = 16384;    // faces
constexpr int NP = 8192;     // query points per batch
constexpr float F_EPS = 1e-3f;
constexpr float F_WEIGHT = 1000.0f;
constexpr float BIAS = 1e-3f;        // keeps dist^2 > 0 despite bf16 rounding

constexpr int PT_TILES = NP / 32;        // 256 point tiles (32-wide) / batch
constexpr int FC_TILES = NF / 32;        // 512 face tiles (32-wide) / batch
constexpr int TPB = 256;                 // 4 waves
constexpr int FS = 16;                   // face slices
constexpr int SL_TILES = FC_TILES / FS;  // 32 face tiles (1024 faces) / slice
constexpr int CH = 16;                   // face tiles per LDS chunk (16 KB)
constexpr int NCHUNK = SL_TILES / CH;    // 2
constexpr int PGB = 32;                  // point groups (256 pts) / batch
// grid = PGB x FS x NB = 2048 blocks

union FragU { uint4 u; short8 s; };

__device__ inline unsigned f2bf(float f) {           // fp32 -> bf16 (RNE)
    unsigned u = __float_as_uint(f);
    return (u + 0x7FFFu + ((u >> 16) & 1u)) >> 16;
}
__device__ inline float bf2f(unsigned h) { return __uint_as_float(h << 16); }
__device__ inline unsigned pk(unsigned lo, unsigned hi) {
    return (lo & 0xFFFFu) | (hi << 16);
}

// ---------------------------------------------------------------------------
// Fused prep. 32x32x16 MFMA, K=16 fully used. Lane L of an operand tile holds
// elem[idx = L&31][k = (L>>5)*8 + j], j=0..7. K-slot maps:
//  A (point m): k0..2=-2p_hi k3..5=-2p_lo k6..8=-2p_hi k9..11=-2p_lo
//               k12=1 k13=1 k14=p2b_hi k15=p2b_lo
//  B (face n):  k0..5=c_hi,c_hi  k6..11=c_lo,c_lo  k12=c2_hi k13=c2_lo k14=1 k15=1
//  => D[m][n] = p2b[m] + c2[n] - 2 p.c = dist^2 + BIAS > 0
// Also inits keys (0xFF) and acc (0) -- no separate memsets.
// ---------------------------------------------------------------------------
__global__ void prep_kernel(const float* __restrict__ pred,
                            const float* __restrict__ pos,
                            const int*   __restrict__ faces,
                            uint4* __restrict__ a_frags,
                            uint4* __restrict__ b_frags,
                            float4* __restrict__ centers4,
                            float4* __restrict__ normals4,
                            unsigned* __restrict__ keys,
                            float* __restrict__ acc) {
    int i = blockIdx.x * blockDim.x + threadIdx.x;   // [0, NB*NF)
    if (i >= NB * NF) return;
    if (i < 2) acc[i] = 0.0f;

    const unsigned ONE = 0x3F80u;

    // ---- faces ----
    {
        int b = i / NF, f = i & (NF - 1);
        const float* p = pos + (size_t)b * NV * 3;
        int i0 = faces[3 * (size_t)i], i1 = faces[3 * (size_t)i + 1], i2 = faces[3 * (size_t)i + 2];
        float ax = p[3 * i0], ay = p[3 * i0 + 1], az = p[3 * i0 + 2];
        float bx = p[3 * i1], by = p[3 * i1 + 1], bz = p[3 * i1 + 2];
        float cx = p[3 * i2], cy = p[3 * i2 + 1], cz = p[3 * i2 + 2];

        const float third = 1.0f / 3.0f;
        float mx = (ax + bx + cx) * third;
        float my = (ay + by + cy) * third;
        float mz = (az + bz + cz) * third;
        float c2 = mx * mx + my * my + mz * mz;

        float e1x = bx - ax, e1y = by - ay, e1z = bz - az;
        float e2x = cx - ax, e2y = cy - ay, e2z = cz - az;
        float nx = e1y * e2z - e1z * e2y;
        float ny = e1z * e2x - e1x * e2z;
        float nz = e1x * e2y - e1y * e2x;
        float len = sqrtf(nx * nx + ny * ny + nz * nz);
        float inv = 1.0f / fmaxf(len, 1e-12f);

        centers4[i] = make_float4(mx, my, mz, c2);
        normals4[i] = make_float4(nx * inv, ny * inv, nz * inv, 0.0f);

        unsigned bhx = f2bf(mx), bhy = f2bf(my), bhz = f2bf(mz);
        unsigned blx = f2bf(mx - bf2f(bhx)), bly = f2bf(my - bf2f(bhy)), blz = f2bf(mz - bf2f(bhz));
        unsigned c2h = f2bf(c2);
        unsigned c2l = f2bf(c2 - bf2f(c2h));

        int tile = f >> 5, n = f & 31;
        uint4* bb = b_frags + (size_t)(b * FC_TILES + tile) * 64;
        bb[n]      = make_uint4(pk(bhx, bhy), pk(bhz, bhx), pk(bhy, bhz), pk(blx, bly)); // k0..7
        bb[32 + n] = make_uint4(pk(blz, blx), pk(bly, blz), pk(c2h, c2l), pk(ONE, ONE)); // k8..15
    }

    // ---- points ----
    if (i < NB * NP) {
        keys[i] = 0xFFFFFFFFu;
        int pb = i / NP, pn = i & (NP - 1);
        float x = pred[3 * (size_t)i], y = pred[3 * (size_t)i + 1], z = pred[3 * (size_t)i + 2];
        unsigned hx = f2bf(x), hy = f2bf(y), hz = f2bf(z);
        float rx = x - bf2f(hx), ry = y - bf2f(hy), rz = z - bf2f(hz);
        unsigned ahx = f2bf(-2.f * bf2f(hx)), ahy = f2bf(-2.f * bf2f(hy)), ahz = f2bf(-2.f * bf2f(hz));
        unsigned alx = f2bf(-2.f * rx), aly = f2bf(-2.f * ry), alz = f2bf(-2.f * rz);
        float p2 = x * x + y * y + z * z + BIAS;
        unsigned p2h = f2bf(p2);
        unsigned p2l = f2bf(p2 - bf2f(p2h));

        int tile = pn >> 5, m = pn & 31;
        uint4* ab = a_frags + (size_t)(pb * PT_TILES + tile) * 64;
        ab[m]      = make_uint4(pk(ahx, ahy), pk(ahz, alx), pk(aly, alz), pk(ahx, ahy)); // k0..7
        ab[32 + m] = make_uint4(pk(ahz, alx), pk(aly, alz), pk(ONE, ONE), pk(p2h, p2l)); // k8..15
    }
}

// ---------------------------------------------------------------------------
// 1-NN on the matrix pipe: 32x32x16 MFMA + LDS-staged B tiles.
// __launch_bounds__(TPB, 1): lift the occupancy-driven VGPR cap. r7's
// VGPR_Count=64 forced best[]/D into AGPRs -> v_accvgpr ping-pong was ~4x
// the epilogue VALU (42us measured vs 10us ideal). With min-waves=1 the
// allocator keeps the hot state in arch VGPRs (~140 needed).
// Block = (256 points, 1024-face slice, batch); each wave owns TWO 32-point
// A-tiles. C/D layout (verified r4-r7, absmax 0.0):
//   col(face) = lane&31, row(point) = (reg&3) + 8*(reg>>2) + 4*(lane>>5).
// key = (bits(dist^2+BIAS) & 0xFFFFC000) | face_idx; cross-slice atomicMin.
// ---------------------------------------------------------------------------
__global__ __launch_bounds__(TPB, 1) void nn_kernel(
        const uint4* __restrict__ a_frags,
        const uint4* __restrict__ b_frags,
        unsigned* __restrict__ keys) {
    const int pg = blockIdx.x, sl = blockIdx.y, b = blockIdx.z;
    const int tid = threadIdx.x, wave = tid >> 6, lane = tid & 63;

    __shared__ uint4 sb[CH * 64];        // 16 KB

    // two 32-point A-tiles per wave
    const int t0 = pg * 8 + wave * 2;
    FragU a0, a1;
    a0.u = a_frags[((size_t)(b * PT_TILES + t0)) * 64 + lane];
    a1.u = a_frags[((size_t)(b * PT_TILES + t0 + 1)) * 64 + lane];

    unsigned best0[16], best1[16];
#pragma unroll
    for (int e = 0; e < 16; ++e) { best0[e] = 0xFFFFFFFFu; best1[e] = 0xFFFFFFFFu; }

    const floatx16 zero = {0.f, 0.f, 0.f, 0.f, 0.f, 0.f, 0.f, 0.f,
                           0.f, 0.f, 0.f, 0.f, 0.f, 0.f, 0.f, 0.f};
    const uint4* bp = b_frags + ((size_t)(b * FC_TILES + sl * SL_TILES)) * 64;

    for (int ch = 0; ch < NCHUNK; ++ch) {
        const uint4* gsrc = bp + (size_t)ch * CH * 64;
        __syncthreads();                 // previous chunk fully consumed
#pragma unroll
        for (int k = 0; k < (CH * 64) / TPB; ++k)
            sb[k * TPB + tid] = gsrc[k * TPB + tid];
        __syncthreads();

        unsigned vf = (unsigned)((sl * SL_TILES + ch * CH) * 32 + (lane & 31));
#pragma unroll
        for (int t = 0; t < CH; t += 2) {
            FragU fb0, fb1;
            fb0.u = sb[t * 64 + lane];
            fb1.u = sb[t * 64 + 64 + lane];
            floatx16 d00 = __builtin_amdgcn_mfma_f32_32x32x16_bf16(a0.s, fb0.s, zero, 0, 0, 0);
            floatx16 d01 = __builtin_amdgcn_mfma_f32_32x32x16_bf16(a0.s, fb1.s, zero, 0, 0, 0);
#pragma unroll
            for (int r = 0; r < 16; ++r) {
                unsigned k0 = (__float_as_uint(d00[r]) & 0xFFFFC000u) | vf;
                unsigned k1 = (__float_as_uint(d01[r]) & 0xFFFFC000u) | (vf + 32u);
                best0[r] = min(best0[r], min(k0, k1));   // -> v_min3_u32
            }
            floatx16 d10 = __builtin_amdgcn_mfma_f32_32x32x16_bf16(a1.s, fb0.s, zero, 0, 0, 0);
            floatx16 d11 = __builtin_amdgcn_mfma_f32_32x32x16_bf16(a1.s, fb1.s, zero, 0, 0, 0);
#pragma unroll
            for (int r = 0; r < 16; ++r) {
                unsigned k0 = (__float_as_uint(d10[r]) & 0xFFFFC000u) | vf;
                unsigned k1 = (__float_as_uint(d11[r]) & 0xFFFFC000u) | (vf + 32u);
                best1[r] = min(best1[r], min(k0, k1));
            }
            vf += 64u;
        }
    }

    // min across the 32 face-columns (stays within each 32-lane half)
#pragma unroll
    for (int e = 0; e < 16; ++e) {
        unsigned v0 = best0[e], v1 = best1[e];
#pragma unroll
        for (int m = 1; m < 32; m <<= 1) {
            v0 = min(v0, (unsigned)__shfl_xor((int)v0, m, 64));
            v1 = min(v1, (unsigned)__shfl_xor((int)v1, m, 64));
        }
        best0[e] = v0; best1[e] = v1;
    }
    unsigned* kb = keys + b * NP;
    if ((lane & 31) == 0) {
        int half = lane >> 5;
#pragma unroll
        for (int r = 0; r < 16; ++r) {
            int row = (r & 3) + 8 * (r >> 2) + 4 * half;
            atomicMin(&kb[t0 * 32 + row], best0[r]);
            atomicMin(&kb[(t0 + 1) * 32 + row], best1[r]);
        }
    }
}

// ---------------------------------------------------------------------------
// Per-point signed plane distance -> interp^3 sum + hit count (r2-proven).
// ---------------------------------------------------------------------------
__global__ __launch_bounds__(TPB) void finalize_kernel(
        const float* __restrict__ pred,
        const float4* __restrict__ centers4,
        const float4* __restrict__ normals4,
        const unsigned int* __restrict__ keys,
        float* __restrict__ acc) {
    int i = blockIdx.x * blockDim.x + threadIdx.x;   // 0 .. B*N-1
    float val = 0.0f, cnt = 0.0f;
    if (i < NB * NP) {
        int b = i / NP;
        unsigned key = keys[i];
        int idx = (int)(key & (unsigned)(NF - 1));
        float4 c  = centers4[b * NF + idx];
        float4 nr = normals4[b * NF + idx];
        const float* pp = pred + (size_t)i * 3;
        float dx = pp[0] - c.x, dy = pp[1] - c.y, dz = pp[2] - c.z;
        float dist = dx * nr.x + dy * nr.y + dz * nr.z;
        float t = F_EPS - dist;
        if (t > 0.0f) { cnt = 1.0f; val = t * t * t; }
    }
    for (int off = 32; off > 0; off >>= 1) {
        val += __shfl_down(val, off, 64);
        cnt += __shfl_down(cnt, off, 64);
    }
    __shared__ float sv[TPB / 64], sn[TPB / 64];
    int lane = threadIdx.x & 63, wave = threadIdx.x >> 6;
    if (lane == 0) { sv[wave] = val; sn[wave] = cnt; }
    __syncthreads();
    if (threadIdx.x == 0) {
        float v = 0.0f, cc = 0.0f;
#pragma unroll
        for (int w = 0; w < TPB / 64; ++w) { v += sv[w]; cc += sn[w]; }
        atomicAdd(&acc[0], v);
        atomicAdd(&acc[1], cc);
    }
}

__global__ void out_kernel(const float* __restrict__ acc,
                           float* __restrict__ out) {
    if (threadIdx.x == 0) {
        out[0] = acc[0] * (F_WEIGHT / (float)NB);
        out[1] = acc[1] * (1.0f / (float)(NB * NP));
    }
}

extern "C" void kernel_launch(void* const* d_in, const int* in_sizes, int n_in,
                              void* d_out, int out_size, void* d_ws, size_t ws_size,
                              hipStream_t stream) {
    const float* pred  = (const float*)d_in[0];   // [B,N,3] f32
    const float* opos  = (const float*)d_in[1];   // [B,V,3] f32
    const int*   faces = (const int*)  d_in[2];   // [B,F,3] i32

    char* ws = (char*)d_ws;
    const size_t a_bytes = (size_t)NB * PT_TILES * 64 * 16;   // 1 MiB
    const size_t b_bytes = (size_t)NB * FC_TILES * 64 * 16;   // 2 MiB
    const size_t c_bytes = (size_t)NB * NF * 16;              // 1 MiB
    const size_t k_bytes = (size_t)NB * NP * sizeof(unsigned);// 128 KiB

    uint4*    a_frags  = (uint4*)ws;
    uint4*    b_frags  = (uint4*)(ws + a_bytes);
    float4*   centers4 = (float4*)(ws + a_bytes + b_bytes);
    float4*   normals4 = (float4*)(ws + a_bytes + b_bytes + c_bytes);
    unsigned* keys     = (unsigned*)(ws + a_bytes + b_bytes + 2 * c_bytes);
    float*    acc      = (float*)(ws + a_bytes + b_bytes + 2 * c_bytes + k_bytes);

    prep_kernel<<<(NB * NF + TPB - 1) / TPB, TPB, 0, stream>>>(
        pred, opos, faces, a_frags, b_frags, centers4, normals4, keys, acc);

    nn_kernel<<<dim3(PGB, FS, NB), TPB, 0, stream>>>(a_frags, b_frags, keys);

    finalize_kernel<<<(NB * NP + TPB - 1) / TPB, TPB, 0, stream>>>(
        pred, centers4, normals4, keys, acc);

    out_kernel<<<1, 64, 0, stream>>>(acc, (float*)d_out);
}